// Round 2
// baseline (366.477 us; speedup 1.0000x reference)
//
#include <hip/hip_runtime.h>
#include <hip/hip_bf16.h>

// Problem: B=2048, P=50, C=512, H=7, W=8  ->  M=2048, N=50 (pad 64), K=28672
//   out[b,p] = relu( sum_k x[b,k]^2 + sum_k p[p,k]^2 - 2 * sum_k x[b,k]*p[p,k] )
//
// Round-2 strategy: LDS-free, barrier-free NT-GEMM. MFMA A/B fragments are
// loaded straight from global memory in the native lane layout
// (A[m=lane&15][k=quad*8+j], 16 rows x 64B per fragment -> fully coalesced).
// Each wave owns 16 M-rows x 64 N-cols so x is read exactly once.
// x^2 accumulated in fp32 on the loaded values before bf16 conversion.
// Depth-1 software prefetch; 1024 blocks (4/CU) hide HBM latency.

typedef __bf16 bf16_t;
typedef bf16_t bf16x8 __attribute__((ext_vector_type(8)));
typedef bf16_t bf16x4 __attribute__((ext_vector_type(4)));
typedef float  floatx4 __attribute__((ext_vector_type(4)));

#define KDIM 28672
#define BDIM 2048
#define KSPLIT 32
#define KCHUNK (KDIM / KSPLIT)   // 896
#define STEPS (KCHUNK / 32)      // 28 MFMA k-steps per chunk

// ---------------- kernel 1: prototype -> bf16 [64][K], p2[p] ----------------
__global__ __launch_bounds__(256) void proto_prep(const float* __restrict__ proto,
                                                  bf16_t* __restrict__ pb,
                                                  float* __restrict__ p2) {
    int p = blockIdx.x;   // 0..63
    int t = threadIdx.x;  // 0..255
    float acc = 0.f;
    if (p < 50) {
        const floatx4* src = (const floatx4*)(proto + (long)p * KDIM);
        for (int i = t; i < KDIM / 4; i += 256) {
            floatx4 v = src[i];
            acc += v[0]*v[0] + v[1]*v[1] + v[2]*v[2] + v[3]*v[3];
            bf16x4 o;
            o[0] = (bf16_t)v[0]; o[1] = (bf16_t)v[1];
            o[2] = (bf16_t)v[2]; o[3] = (bf16_t)v[3];
            *(bf16x4*)(pb + (long)p * KDIM + i * 4) = o;
        }
    } else {
        bf16x4 z;
        z[0] = (bf16_t)0.f; z[1] = (bf16_t)0.f; z[2] = (bf16_t)0.f; z[3] = (bf16_t)0.f;
        for (int i = t; i < KDIM / 4; i += 256)
            *(bf16x4*)(pb + (long)p * KDIM + i * 4) = z;
    }
    __shared__ float sred[256];
    sred[t] = acc;
    __syncthreads();
    for (int s = 128; s > 0; s >>= 1) {
        if (t < s) sred[t] += sred[t + s];
        __syncthreads();
    }
    if (t == 0) p2[p] = (p < 50) ? sred[0] : 0.f;
}

// ---------------- kernel 2: main fused GEMM + x2 (no LDS, no barriers) ------
// grid (32, 32): blockIdx.x = M-tile (64 rows), blockIdx.y = K-split
__global__ __launch_bounds__(256, 4) void proto_main(const float* __restrict__ x,
                                                     const bf16_t* __restrict__ pb,
                                                     float* __restrict__ xpp,
                                                     float* __restrict__ x2p) {
    const int t = threadIdx.x;
    const int lane = t & 63;
    const int wave = t >> 6;          // 0..3: owns 16 M-rows
    const int lr = lane & 15;
    const int quad = lane >> 4;       // 0..3: k sub-slice within MFMA step
    const int mbase = blockIdx.x * 64;
    const int ks = blockIdx.y;
    const int kbase = ks * KCHUNK;

    // A: x row (fp32), native fragment layout
    const int mrow = mbase + wave * 16 + lr;
    const float* xr = x + (long)mrow * KDIM + kbase + quad * 8;
    // B: proto rows for 4 n-tiles (bf16, L2-resident)
    const bf16_t* pr0 = pb + (long)(0  + lr) * KDIM + kbase + quad * 8;
    const bf16_t* pr1 = pb + (long)(16 + lr) * KDIM + kbase + quad * 8;
    const bf16_t* pr2 = pb + (long)(32 + lr) * KDIM + kbase + quad * 8;
    const bf16_t* pr3 = pb + (long)(48 + lr) * KDIM + kbase + quad * 8;

    floatx4 acc0 = {0.f,0.f,0.f,0.f};
    floatx4 acc1 = {0.f,0.f,0.f,0.f};
    floatx4 acc2 = {0.f,0.f,0.f,0.f};
    floatx4 acc3 = {0.f,0.f,0.f,0.f};
    float x2acc = 0.f;

    // prologue: load step 0
    floatx4 a0 = *(const floatx4*)(xr);
    floatx4 a1 = *(const floatx4*)(xr + 4);
    bf16x8 b0 = *(const bf16x8*)(pr0);
    bf16x8 b1 = *(const bf16x8*)(pr1);
    bf16x8 b2 = *(const bf16x8*)(pr2);
    bf16x8 b3 = *(const bf16x8*)(pr3);

    for (int it = 0; it < STEPS; ++it) {
        // prefetch next step (wrap to 0 on last iter -> branchless, harmless reload)
        const int nk = (it + 1 < STEPS ? it + 1 : 0) * 32;
        floatx4 na0 = *(const floatx4*)(xr + nk);
        floatx4 na1 = *(const floatx4*)(xr + nk + 4);
        bf16x8 nb0 = *(const bf16x8*)(pr0 + nk);
        bf16x8 nb1 = *(const bf16x8*)(pr1 + nk);
        bf16x8 nb2 = *(const bf16x8*)(pr2 + nk);
        bf16x8 nb3 = *(const bf16x8*)(pr3 + nk);

        // fused x^2 in fp32 (exact), then convert A to bf16
        x2acc += a0[0]*a0[0] + a0[1]*a0[1] + a0[2]*a0[2] + a0[3]*a0[3]
               + a1[0]*a1[0] + a1[1]*a1[1] + a1[2]*a1[2] + a1[3]*a1[3];
        bf16x8 av;
        av[0] = (bf16_t)a0[0]; av[1] = (bf16_t)a0[1];
        av[2] = (bf16_t)a0[2]; av[3] = (bf16_t)a0[3];
        av[4] = (bf16_t)a1[0]; av[5] = (bf16_t)a1[1];
        av[6] = (bf16_t)a1[2]; av[7] = (bf16_t)a1[3];

        acc0 = __builtin_amdgcn_mfma_f32_16x16x32_bf16(av, b0, acc0, 0, 0, 0);
        acc1 = __builtin_amdgcn_mfma_f32_16x16x32_bf16(av, b1, acc1, 0, 0, 0);
        acc2 = __builtin_amdgcn_mfma_f32_16x16x32_bf16(av, b2, acc2, 0, 0, 0);
        acc3 = __builtin_amdgcn_mfma_f32_16x16x32_bf16(av, b3, acc3, 0, 0, 0);

        a0 = na0; a1 = na1;
        b0 = nb0; b1 = nb1; b2 = nb2; b3 = nb3;
    }

    // x2: lane's partial covers quad's k-slices of row (lane&15);
    // butterfly over the quad bits to sum the 4 quads.
    x2acc += __shfl_xor(x2acc, 16, 64);
    x2acc += __shfl_xor(x2acc, 32, 64);
    if (quad == 0)
        x2p[ks * BDIM + mbase + wave * 16 + lr] = x2acc;

    // xp partials: C/D layout col(n) = lane&15, row(m) = quad*4 + r
    const long base = ((long)ks * BDIM + mbase + wave * 16) * 64;
    #pragma unroll
    for (int r = 0; r < 4; ++r) {
        const int mr = quad * 4 + r;
        xpp[base + (long)mr * 64 + 0  + lr] = acc0[r];
        xpp[base + (long)mr * 64 + 16 + lr] = acc1[r];
        xpp[base + (long)mr * 64 + 32 + lr] = acc2[r];
        xpp[base + (long)mr * 64 + 48 + lr] = acc3[r];
    }
}

// ---------------- kernel 3: reduce split-K + epilogue ----------------
__global__ __launch_bounds__(256) void proto_finalize(const float* __restrict__ xpp,
                                                      const float* __restrict__ x2p,
                                                      const float* __restrict__ p2,
                                                      float* __restrict__ out) {
    int idx = blockIdx.x * 256 + threadIdx.x;  // 0 .. 2048*64-1
    int b = idx >> 6;
    int n = idx & 63;
    if (n >= 50) return;
    float xp = 0.f, x2 = 0.f;
    #pragma unroll
    for (int ksi = 0; ksi < KSPLIT; ++ksi) {
        xp += xpp[((long)ksi * BDIM + b) * 64 + n];
        x2 += x2p[ksi * BDIM + b];
    }
    float d = x2 + p2[n] - 2.f * xp;
    out[b * 50 + n] = d > 0.f ? d : 0.f;
}

// ---------------- launch ----------------
extern "C" void kernel_launch(void* const* d_in, const int* in_sizes, int n_in,
                              void* d_out, int out_size, void* d_ws, size_t ws_size,
                              hipStream_t stream) {
    const float* x = (const float*)d_in[0];
    const float* proto = (const float*)d_in[1];
    float* out = (float*)d_out;

    char* ws = (char*)d_ws;
    // ws layout (bytes):
    //   [0)           proto_bf16: 64*28672*2      = 3,670,016
    //   [3,670,016)   p2:         64*4            = 256
    //   [3,670,272)   x2p:        32*2048*4       = 262,144
    //   [3,932,416)   xpp:        32*2048*64*4    = 16,777,216   (total ~20.7 MB)
    bf16_t* pb  = (bf16_t*)(ws);
    float*  p2  = (float*)(ws + 3670016);
    float*  x2p = (float*)(ws + 3670272);
    float*  xpp = (float*)(ws + 3932416);

    proto_prep<<<64, 256, 0, stream>>>(proto, pb, p2);
    proto_main<<<dim3(32, KSPLIT), 256, 0, stream>>>(x, pb, xpp, x2p);
    proto_finalize<<<(BDIM * 64) / 256, 256, 0, stream>>>(xpp, x2p, p2, out);
}

// Round 3
// 350.848 us; speedup vs baseline: 1.0445x; 1.0445x over previous
//
#include <hip/hip_runtime.h>
#include <hip/hip_bf16.h>

// Problem: B=2048, P=50, C=512, H=7, W=8  ->  M=2048, N=50 (pad 64), K=28672
//   out[b,p] = relu( sum_k x[b,k]^2 + sum_k p[p,k]^2 - 2 * sum_k x[b,k]*p[p,k] )
//
// Round-3: register-staged A (coalesced, exact fp32 x^2) -> bf16 -> LDS
// (double-buffered, ONE barrier/iter), depth-1 register prefetch of A,
// per-lane B fragments straight from L2. 1024 blocks = 4 blocks/CU.

typedef __bf16 bf16_t;
typedef bf16_t bf16x8 __attribute__((ext_vector_type(8)));
typedef bf16_t bf16x4 __attribute__((ext_vector_type(4)));
typedef float  floatx4 __attribute__((ext_vector_type(4)));

#define KDIM 28672
#define BDIM 2048
#define KSPLIT 32
#define KCHUNK (KDIM / KSPLIT)   // 896
#define STEPS (KCHUNK / 64)      // 14 k-steps of 64 per chunk
#define ASTRIDE 72               // LDS row stride in bf16 (64 + 8 pad): bank-uniform

// ---------------- kernel 1: prototype -> bf16 [64][K], p2[p] ----------------
__global__ __launch_bounds__(256) void proto_prep(const float* __restrict__ proto,
                                                  bf16_t* __restrict__ pb,
                                                  float* __restrict__ p2) {
    int p = blockIdx.x;   // 0..63
    int t = threadIdx.x;  // 0..255
    float acc = 0.f;
    if (p < 50) {
        const floatx4* src = (const floatx4*)(proto + (long)p * KDIM);
        for (int i = t; i < KDIM / 4; i += 256) {
            floatx4 v = src[i];
            acc += v[0]*v[0] + v[1]*v[1] + v[2]*v[2] + v[3]*v[3];
            bf16x4 o;
            o[0] = (bf16_t)v[0]; o[1] = (bf16_t)v[1];
            o[2] = (bf16_t)v[2]; o[3] = (bf16_t)v[3];
            *(bf16x4*)(pb + (long)p * KDIM + i * 4) = o;
        }
    } else {
        bf16x4 z;
        z[0] = (bf16_t)0.f; z[1] = (bf16_t)0.f; z[2] = (bf16_t)0.f; z[3] = (bf16_t)0.f;
        for (int i = t; i < KDIM / 4; i += 256)
            *(bf16x4*)(pb + (long)p * KDIM + i * 4) = z;
    }
    __shared__ float sred[256];
    sred[t] = acc;
    __syncthreads();
    for (int s = 128; s > 0; s >>= 1) {
        if (t < s) sred[t] += sred[t + s];
        __syncthreads();
    }
    if (t == 0) p2[p] = (p < 50) ? sred[0] : 0.f;
}

// ---------------- kernel 2: main fused GEMM + x2 ----------------
// grid (32, 32): blockIdx.x = M-tile (64 rows), blockIdx.y = K-split
__global__ __launch_bounds__(256, 4) void proto_main(const float* __restrict__ x,
                                                     const bf16_t* __restrict__ pb,
                                                     float* __restrict__ xpp,
                                                     float* __restrict__ x2p) {
    __shared__ bf16_t As[2][64 * ASTRIDE];   // 2 x 9216 B

    const int t = threadIdx.x;
    const int lane = t & 63;
    const int wave = t >> 6;
    const int lr = lane & 15;
    const int q  = lane >> 4;
    const int mbase = blockIdx.x * 64;
    const int ks = blockIdx.y;
    const int kbase = ks * KCHUNK;

    // ---- staging role: 4 threads per row, 16 consecutive floats each ----
    const int srow = t >> 2;
    const int sq   = t & 3;
    const float* xrow = x + (long)(mbase + srow) * KDIM + kbase + sq * 16;
    bf16_t* const awr[2] = { &As[0][srow * ASTRIDE + sq * 16],
                             &As[1][srow * ASTRIDE + sq * 16] };

    // ---- compute role: 2x2 wave split over 64x64 tile ----
    const int m0 = (wave >> 1) * 32;
    const int n0 = (wave & 1) * 32;
    const bf16_t* pbr0 = pb + (long)(n0 + lr) * KDIM + kbase + q * 8;
    const bf16_t* pbr1 = pb + (long)(n0 + 16 + lr) * KDIM + kbase + q * 8;
    const int ard0 = (m0 + lr) * ASTRIDE + q * 8;        // a-frag LDS offsets
    const int ard1 = (m0 + 16 + lr) * ASTRIDE + q * 8;

    floatx4 acc00 = {0.f,0.f,0.f,0.f};
    floatx4 acc01 = {0.f,0.f,0.f,0.f};
    floatx4 acc10 = {0.f,0.f,0.f,0.f};
    floatx4 acc11 = {0.f,0.f,0.f,0.f};
    float x2acc = 0.f;

    // ---- prologue: step 0 -> regs -> x2/convert -> LDS[0]; step 1 -> regs ----
    floatx4 c0 = *(const floatx4*)(xrow);
    floatx4 c1 = *(const floatx4*)(xrow + 4);
    floatx4 c2 = *(const floatx4*)(xrow + 8);
    floatx4 c3 = *(const floatx4*)(xrow + 12);
    {
        x2acc += c0[0]*c0[0] + c0[1]*c0[1] + c0[2]*c0[2] + c0[3]*c0[3]
               + c1[0]*c1[0] + c1[1]*c1[1] + c1[2]*c1[2] + c1[3]*c1[3]
               + c2[0]*c2[0] + c2[1]*c2[1] + c2[2]*c2[2] + c2[3]*c2[3]
               + c3[0]*c3[0] + c3[1]*c3[1] + c3[2]*c3[2] + c3[3]*c3[3];
        bf16x8 lo, hi;
        lo[0]=(bf16_t)c0[0]; lo[1]=(bf16_t)c0[1]; lo[2]=(bf16_t)c0[2]; lo[3]=(bf16_t)c0[3];
        lo[4]=(bf16_t)c1[0]; lo[5]=(bf16_t)c1[1]; lo[6]=(bf16_t)c1[2]; lo[7]=(bf16_t)c1[3];
        hi[0]=(bf16_t)c2[0]; hi[1]=(bf16_t)c2[1]; hi[2]=(bf16_t)c2[2]; hi[3]=(bf16_t)c2[3];
        hi[4]=(bf16_t)c3[0]; hi[5]=(bf16_t)c3[1]; hi[6]=(bf16_t)c3[2]; hi[7]=(bf16_t)c3[3];
        *(bf16x8*)(awr[0])     = lo;
        *(bf16x8*)(awr[0] + 8) = hi;
    }
    // load step 1 into cur regs
    c0 = *(const floatx4*)(xrow + 64);
    c1 = *(const floatx4*)(xrow + 68);
    c2 = *(const floatx4*)(xrow + 72);
    c3 = *(const floatx4*)(xrow + 76);
    __syncthreads();

    // ---- main loop: iter it MFMAs step it (LDS[it&1]), converts step it+1,
    //      prefetches step it+2. ONE barrier per iter. ----
    #pragma unroll 2
    for (int it = 0; it < STEPS; ++it) {
        const int buf = it & 1;

        // B fragments for CURRENT step (issued first: MFMA's vmcnt wait
        // retires these without retiring the A prefetch below)
        const int ko = it * 64;
        bf16x8 b00 = *(const bf16x8*)(pbr0 + ko);
        bf16x8 b01 = *(const bf16x8*)(pbr0 + ko + 32);
        bf16x8 b10 = *(const bf16x8*)(pbr1 + ko);
        bf16x8 b11 = *(const bf16x8*)(pbr1 + ko + 32);

        // A prefetch: step it+2 (wrap-clamped; surplus reload harmless)
        const int nk = (it + 2 < STEPS ? it + 2 : STEPS - 1) * 64;
        floatx4 n0v = *(const floatx4*)(xrow + nk);
        floatx4 n1v = *(const floatx4*)(xrow + nk + 4);
        floatx4 n2v = *(const floatx4*)(xrow + nk + 8);
        floatx4 n3v = *(const floatx4*)(xrow + nk + 12);

        // convert step it+1 (loaded one full iteration ago) -> LDS[buf^1]
        if (it + 1 < STEPS) {
            x2acc += c0[0]*c0[0] + c0[1]*c0[1] + c0[2]*c0[2] + c0[3]*c0[3]
                   + c1[0]*c1[0] + c1[1]*c1[1] + c1[2]*c1[2] + c1[3]*c1[3]
                   + c2[0]*c2[0] + c2[1]*c2[1] + c2[2]*c2[2] + c2[3]*c2[3]
                   + c3[0]*c3[0] + c3[1]*c3[1] + c3[2]*c3[2] + c3[3]*c3[3];
            bf16x8 lo, hi;
            lo[0]=(bf16_t)c0[0]; lo[1]=(bf16_t)c0[1]; lo[2]=(bf16_t)c0[2]; lo[3]=(bf16_t)c0[3];
            lo[4]=(bf16_t)c1[0]; lo[5]=(bf16_t)c1[1]; lo[6]=(bf16_t)c1[2]; lo[7]=(bf16_t)c1[3];
            hi[0]=(bf16_t)c2[0]; hi[1]=(bf16_t)c2[1]; hi[2]=(bf16_t)c2[2]; hi[3]=(bf16_t)c2[3];
            hi[4]=(bf16_t)c3[0]; hi[5]=(bf16_t)c3[1]; hi[6]=(bf16_t)c3[2]; hi[7]=(bf16_t)c3[3];
            *(bf16x8*)(awr[buf ^ 1])     = lo;
            *(bf16x8*)(awr[buf ^ 1] + 8) = hi;
        }

        // MFMA current step from LDS[buf]
        {
            const bf16_t* ab = &As[buf][0];
            bf16x8 a00 = *(const bf16x8*)(ab + ard0);        // m-tile0, k 0..31
            bf16x8 a01 = *(const bf16x8*)(ab + ard0 + 32);   // m-tile0, k 32..63
            bf16x8 a10 = *(const bf16x8*)(ab + ard1);
            bf16x8 a11 = *(const bf16x8*)(ab + ard1 + 32);
            acc00 = __builtin_amdgcn_mfma_f32_16x16x32_bf16(a00, b00, acc00, 0, 0, 0);
            acc10 = __builtin_amdgcn_mfma_f32_16x16x32_bf16(a10, b00, acc10, 0, 0, 0);
            acc01 = __builtin_amdgcn_mfma_f32_16x16x32_bf16(a00, b10, acc01, 0, 0, 0);
            acc11 = __builtin_amdgcn_mfma_f32_16x16x32_bf16(a10, b10, acc11, 0, 0, 0);
            acc00 = __builtin_amdgcn_mfma_f32_16x16x32_bf16(a01, b01, acc00, 0, 0, 0);
            acc10 = __builtin_amdgcn_mfma_f32_16x16x32_bf16(a11, b01, acc10, 0, 0, 0);
            acc01 = __builtin_amdgcn_mfma_f32_16x16x32_bf16(a01, b11, acc01, 0, 0, 0);
            acc11 = __builtin_amdgcn_mfma_f32_16x16x32_bf16(a11, b11, acc11, 0, 0, 0);
        }

        __syncthreads();   // LDS[buf^1] visible; LDS[buf] free to overwrite
        c0 = n0v; c1 = n1v; c2 = n2v; c3 = n3v;
    }

    // ---- xp partials: C/D layout col(n)=lane&15, row(m)=q*4+r ----
    const long base = ((long)ks * BDIM + mbase) * 64;
    #pragma unroll
    for (int r = 0; r < 4; ++r) {
        const int mr = m0 + q * 4 + r;
        xpp[base + (long)mr * 64 + n0 + lr]             = acc00[r];
        xpp[base + (long)mr * 64 + n0 + 16 + lr]        = acc01[r];
        xpp[base + (long)(mr + 16) * 64 + n0 + lr]      = acc10[r];
        xpp[base + (long)(mr + 16) * 64 + n0 + 16 + lr] = acc11[r];
    }

    // ---- x2 partials: 4 staging threads per row -> LDS reduce ----
    float* red = (float*)&As[0][0];
    red[t] = x2acc;          // safe: final loop barrier already executed
    __syncthreads();
    if (t < 64) {
        float s = red[4 * t] + red[4 * t + 1] + red[4 * t + 2] + red[4 * t + 3];
        x2p[ks * BDIM + mbase + t] = s;
    }
}

// ---------------- kernel 3: reduce split-K + epilogue ----------------
__global__ __launch_bounds__(256) void proto_finalize(const float* __restrict__ xpp,
                                                      const float* __restrict__ x2p,
                                                      const float* __restrict__ p2,
                                                      float* __restrict__ out) {
    int idx = blockIdx.x * 256 + threadIdx.x;  // 0 .. 2048*64-1
    int b = idx >> 6;
    int n = idx & 63;
    if (n >= 50) return;
    float xp = 0.f, x2 = 0.f;
    #pragma unroll
    for (int ksi = 0; ksi < KSPLIT; ++ksi) {
        xp += xpp[((long)ksi * BDIM + b) * 64 + n];
        x2 += x2p[ksi * BDIM + b];
    }
    float d = x2 + p2[n] - 2.f * xp;
    out[b * 50 + n] = d > 0.f ? d : 0.f;
}

// ---------------- launch ----------------
extern "C" void kernel_launch(void* const* d_in, const int* in_sizes, int n_in,
                              void* d_out, int out_size, void* d_ws, size_t ws_size,
                              hipStream_t stream) {
    const float* x = (const float*)d_in[0];
    const float* proto = (const float*)d_in[1];
    float* out = (float*)d_out;

    char* ws = (char*)d_ws;
    // ws layout (bytes):
    //   [0)           proto_bf16: 64*28672*2      = 3,670,016
    //   [3,670,016)   p2:         64*4            = 256
    //   [3,670,272)   x2p:        32*2048*4       = 262,144
    //   [3,932,416)   xpp:        32*2048*64*4    = 16,777,216   (total ~20.7 MB)
    bf16_t* pb  = (bf16_t*)(ws);
    float*  p2  = (float*)(ws + 3670016);
    float*  x2p = (float*)(ws + 3670272);
    float*  xpp = (float*)(ws + 3932416);

    proto_prep<<<64, 256, 0, stream>>>(proto, pb, p2);
    proto_main<<<dim3(32, KSPLIT), 256, 0, stream>>>(x, pb, xpp, x2p);
    proto_finalize<<<(BDIM * 64) / 256, 256, 0, stream>>>(xpp, x2p, p2, out);
}

// Round 4
// 340.594 us; speedup vs baseline: 1.0760x; 1.0301x over previous
//
#include <hip/hip_runtime.h>
#include <hip/hip_bf16.h>

// Problem: B=2048, P=50, C=512, H=7, W=8  ->  M=2048, N=50 (pad 64), K=28672
//   out[b,p] = relu( sum_k x[b,k]^2 + sum_k p[p,k]^2 - 2 * sum_k x[b,k]*p[p,k] )
//
// Round-4: (a) proto_prep split-K 8x -> 512 blocks (was 64, latency-bound);
// (b) proto_main adds depth-1 B prefetch (B had 0 slack vs L2 latency; A keeps
// 2-step slack vs HBM latency); double-buffered LDS, ONE barrier/iter,
// 1024 blocks = 4 blocks/CU. x read exactly once (235 MB, HBM-bound floor).

typedef __bf16 bf16_t;
typedef bf16_t bf16x8 __attribute__((ext_vector_type(8)));
typedef bf16_t bf16x4 __attribute__((ext_vector_type(4)));
typedef float  floatx4 __attribute__((ext_vector_type(4)));

#define KDIM 28672
#define BDIM 2048
#define KSPLIT 32
#define KCHUNK (KDIM / KSPLIT)   // 896
#define STEPS (KCHUNK / 64)      // 14 k-steps of 64 per chunk
#define ASTRIDE 72               // LDS row stride in bf16 (64 + 8 pad)
#define PREPSPLIT 8
#define PREPCHUNK (KDIM / PREPSPLIT)  // 3584 floats = 896 float4

// ---------------- kernel 1: prototype -> bf16 [64][K], p2 partials ----------
// grid (64, 8): blockIdx.x = p, blockIdx.y = k-chunk
__global__ __launch_bounds__(256) void proto_prep(const float* __restrict__ proto,
                                                  bf16_t* __restrict__ pb,
                                                  float* __restrict__ p2p) {
    const int p = blockIdx.x;   // 0..63
    const int kc = blockIdx.y;  // 0..7
    const int t = threadIdx.x;  // 0..255
    float acc = 0.f;
    if (p < 50) {
        const floatx4* src = (const floatx4*)(proto + (long)p * KDIM + kc * PREPCHUNK);
        bf16_t* dst = pb + (long)p * KDIM + kc * PREPCHUNK;
        for (int i = t; i < PREPCHUNK / 4; i += 256) {
            floatx4 v = src[i];
            acc += v[0]*v[0] + v[1]*v[1] + v[2]*v[2] + v[3]*v[3];
            bf16x4 o;
            o[0] = (bf16_t)v[0]; o[1] = (bf16_t)v[1];
            o[2] = (bf16_t)v[2]; o[3] = (bf16_t)v[3];
            *(bf16x4*)(dst + i * 4) = o;
        }
    } else {
        bf16_t* dst = pb + (long)p * KDIM + kc * PREPCHUNK;
        bf16x4 z;
        z[0] = (bf16_t)0.f; z[1] = (bf16_t)0.f; z[2] = (bf16_t)0.f; z[3] = (bf16_t)0.f;
        for (int i = t; i < PREPCHUNK / 4; i += 256)
            *(bf16x4*)(dst + i * 4) = z;
    }
    __shared__ float sred[256];
    sred[t] = acc;
    __syncthreads();
    for (int s = 128; s > 0; s >>= 1) {
        if (t < s) sred[t] += sred[t + s];
        __syncthreads();
    }
    if (t == 0) p2p[kc * 64 + p] = (p < 50) ? sred[0] : 0.f;
}

// ---------------- kernel 2: main fused GEMM + x2 ----------------
// grid (32, 32): blockIdx.x = M-tile (64 rows), blockIdx.y = K-split
__global__ __launch_bounds__(256, 4) void proto_main(const float* __restrict__ x,
                                                     const bf16_t* __restrict__ pb,
                                                     float* __restrict__ xpp,
                                                     float* __restrict__ x2p) {
    __shared__ bf16_t As[2][64 * ASTRIDE];   // 2 x 9216 B

    const int t = threadIdx.x;
    const int lane = t & 63;
    const int wave = t >> 6;
    const int lr = lane & 15;
    const int q  = lane >> 4;
    const int mbase = blockIdx.x * 64;
    const int ks = blockIdx.y;
    const int kbase = ks * KCHUNK;

    // ---- staging role: 4 threads per row, 16 consecutive floats each ----
    const int srow = t >> 2;
    const int sq   = t & 3;
    const float* xrow = x + (long)(mbase + srow) * KDIM + kbase + sq * 16;
    bf16_t* const awr[2] = { &As[0][srow * ASTRIDE + sq * 16],
                             &As[1][srow * ASTRIDE + sq * 16] };

    // ---- compute role: 2x2 wave split over 64x64 tile ----
    const int m0 = (wave >> 1) * 32;
    const int n0 = (wave & 1) * 32;
    const bf16_t* pbr0 = pb + (long)(n0 + lr) * KDIM + kbase + q * 8;
    const bf16_t* pbr1 = pb + (long)(n0 + 16 + lr) * KDIM + kbase + q * 8;
    const int ard0 = (m0 + lr) * ASTRIDE + q * 8;
    const int ard1 = (m0 + 16 + lr) * ASTRIDE + q * 8;

    floatx4 acc00 = {0.f,0.f,0.f,0.f};
    floatx4 acc01 = {0.f,0.f,0.f,0.f};
    floatx4 acc10 = {0.f,0.f,0.f,0.f};
    floatx4 acc11 = {0.f,0.f,0.f,0.f};
    float x2acc = 0.f;

    // ---- prologue ----
    // step 0 A -> regs -> x2/convert -> LDS[0]
    floatx4 c0 = *(const floatx4*)(xrow);
    floatx4 c1 = *(const floatx4*)(xrow + 4);
    floatx4 c2 = *(const floatx4*)(xrow + 8);
    floatx4 c3 = *(const floatx4*)(xrow + 12);
    // step 0 B -> regs
    bf16x8 bc00 = *(const bf16x8*)(pbr0);
    bf16x8 bc01 = *(const bf16x8*)(pbr0 + 32);
    bf16x8 bc10 = *(const bf16x8*)(pbr1);
    bf16x8 bc11 = *(const bf16x8*)(pbr1 + 32);
    {
        x2acc += c0[0]*c0[0] + c0[1]*c0[1] + c0[2]*c0[2] + c0[3]*c0[3]
               + c1[0]*c1[0] + c1[1]*c1[1] + c1[2]*c1[2] + c1[3]*c1[3]
               + c2[0]*c2[0] + c2[1]*c2[1] + c2[2]*c2[2] + c2[3]*c2[3]
               + c3[0]*c3[0] + c3[1]*c3[1] + c3[2]*c3[2] + c3[3]*c3[3];
        bf16x8 lo, hi;
        lo[0]=(bf16_t)c0[0]; lo[1]=(bf16_t)c0[1]; lo[2]=(bf16_t)c0[2]; lo[3]=(bf16_t)c0[3];
        lo[4]=(bf16_t)c1[0]; lo[5]=(bf16_t)c1[1]; lo[6]=(bf16_t)c1[2]; lo[7]=(bf16_t)c1[3];
        hi[0]=(bf16_t)c2[0]; hi[1]=(bf16_t)c2[1]; hi[2]=(bf16_t)c2[2]; hi[3]=(bf16_t)c2[3];
        hi[4]=(bf16_t)c3[0]; hi[5]=(bf16_t)c3[1]; hi[6]=(bf16_t)c3[2]; hi[7]=(bf16_t)c3[3];
        *(bf16x8*)(awr[0])     = lo;
        *(bf16x8*)(awr[0] + 8) = hi;
    }
    // step 1 A -> regs
    c0 = *(const floatx4*)(xrow + 64);
    c1 = *(const floatx4*)(xrow + 68);
    c2 = *(const floatx4*)(xrow + 72);
    c3 = *(const floatx4*)(xrow + 76);
    __syncthreads();

    // ---- main loop: iter it MFMAs step it (LDS[it&1], B regs), converts
    //      step it+1 -> LDS[buf^1], prefetches A step it+2 and B step it+1.
    //      ONE barrier per iter. ----
    #pragma unroll 2
    for (int it = 0; it < STEPS; ++it) {
        const int buf = it & 1;

        // B prefetch: step it+1 (L2-resident; 1 iter of slack)
        const int nk1 = (it + 1 < STEPS ? it + 1 : STEPS - 1) * 64;
        bf16x8 bn00 = *(const bf16x8*)(pbr0 + nk1);
        bf16x8 bn01 = *(const bf16x8*)(pbr0 + nk1 + 32);
        bf16x8 bn10 = *(const bf16x8*)(pbr1 + nk1);
        bf16x8 bn11 = *(const bf16x8*)(pbr1 + nk1 + 32);

        // A prefetch: step it+2 (HBM; 2 iters of slack)
        const int nk2 = (it + 2 < STEPS ? it + 2 : STEPS - 1) * 64;
        floatx4 n0v = *(const floatx4*)(xrow + nk2);
        floatx4 n1v = *(const floatx4*)(xrow + nk2 + 4);
        floatx4 n2v = *(const floatx4*)(xrow + nk2 + 8);
        floatx4 n3v = *(const floatx4*)(xrow + nk2 + 12);

        // convert step it+1 (loaded one full iteration ago) -> LDS[buf^1]
        if (it + 1 < STEPS) {
            x2acc += c0[0]*c0[0] + c0[1]*c0[1] + c0[2]*c0[2] + c0[3]*c0[3]
                   + c1[0]*c1[0] + c1[1]*c1[1] + c1[2]*c1[2] + c1[3]*c1[3]
                   + c2[0]*c2[0] + c2[1]*c2[1] + c2[2]*c2[2] + c2[3]*c2[3]
                   + c3[0]*c3[0] + c3[1]*c3[1] + c3[2]*c3[2] + c3[3]*c3[3];
            bf16x8 lo, hi;
            lo[0]=(bf16_t)c0[0]; lo[1]=(bf16_t)c0[1]; lo[2]=(bf16_t)c0[2]; lo[3]=(bf16_t)c0[3];
            lo[4]=(bf16_t)c1[0]; lo[5]=(bf16_t)c1[1]; lo[6]=(bf16_t)c1[2]; lo[7]=(bf16_t)c1[3];
            hi[0]=(bf16_t)c2[0]; hi[1]=(bf16_t)c2[1]; hi[2]=(bf16_t)c2[2]; hi[3]=(bf16_t)c2[3];
            hi[4]=(bf16_t)c3[0]; hi[5]=(bf16_t)c3[1]; hi[6]=(bf16_t)c3[2]; hi[7]=(bf16_t)c3[3];
            *(bf16x8*)(awr[buf ^ 1])     = lo;
            *(bf16x8*)(awr[buf ^ 1] + 8) = hi;
        }

        // MFMA current step: A from LDS[buf], B from regs (loaded last iter)
        {
            const bf16_t* ab = &As[buf][0];
            bf16x8 a00 = *(const bf16x8*)(ab + ard0);
            bf16x8 a01 = *(const bf16x8*)(ab + ard0 + 32);
            bf16x8 a10 = *(const bf16x8*)(ab + ard1);
            bf16x8 a11 = *(const bf16x8*)(ab + ard1 + 32);
            acc00 = __builtin_amdgcn_mfma_f32_16x16x32_bf16(a00, bc00, acc00, 0, 0, 0);
            acc10 = __builtin_amdgcn_mfma_f32_16x16x32_bf16(a10, bc00, acc10, 0, 0, 0);
            acc01 = __builtin_amdgcn_mfma_f32_16x16x32_bf16(a00, bc10, acc01, 0, 0, 0);
            acc11 = __builtin_amdgcn_mfma_f32_16x16x32_bf16(a10, bc10, acc11, 0, 0, 0);
            acc00 = __builtin_amdgcn_mfma_f32_16x16x32_bf16(a01, bc01, acc00, 0, 0, 0);
            acc10 = __builtin_amdgcn_mfma_f32_16x16x32_bf16(a11, bc01, acc10, 0, 0, 0);
            acc01 = __builtin_amdgcn_mfma_f32_16x16x32_bf16(a01, bc11, acc01, 0, 0, 0);
            acc11 = __builtin_amdgcn_mfma_f32_16x16x32_bf16(a11, bc11, acc11, 0, 0, 0);
        }

        __syncthreads();   // LDS[buf^1] visible; LDS[buf] free next iter
        c0 = n0v; c1 = n1v; c2 = n2v; c3 = n3v;
        bc00 = bn00; bc01 = bn01; bc10 = bn10; bc11 = bn11;
    }

    // ---- xp partials: C/D layout col(n)=lane&15, row(m)=q*4+r ----
    const long base = ((long)ks * BDIM + mbase) * 64;
    #pragma unroll
    for (int r = 0; r < 4; ++r) {
        const int mr = m0 + q * 4 + r;
        xpp[base + (long)mr * 64 + n0 + lr]             = acc00[r];
        xpp[base + (long)mr * 64 + n0 + 16 + lr]        = acc01[r];
        xpp[base + (long)(mr + 16) * 64 + n0 + lr]      = acc10[r];
        xpp[base + (long)(mr + 16) * 64 + n0 + 16 + lr] = acc11[r];
    }

    // ---- x2 partials: 4 staging threads per row -> LDS reduce ----
    float* red = (float*)&As[0][0];
    red[t] = x2acc;          // safe: final loop barrier already executed
    __syncthreads();
    if (t < 64) {
        float s = red[4 * t] + red[4 * t + 1] + red[4 * t + 2] + red[4 * t + 3];
        x2p[ks * BDIM + mbase + t] = s;
    }
}

// ---------------- kernel 3: reduce split-K + epilogue ----------------
__global__ __launch_bounds__(256) void proto_finalize(const float* __restrict__ xpp,
                                                      const float* __restrict__ x2p,
                                                      const float* __restrict__ p2p,
                                                      float* __restrict__ out) {
    int idx = blockIdx.x * 256 + threadIdx.x;  // 0 .. 2048*64-1
    int b = idx >> 6;
    int n = idx & 63;
    if (n >= 50) return;
    float xp = 0.f, x2 = 0.f, p2 = 0.f;
    #pragma unroll
    for (int ksi = 0; ksi < KSPLIT; ++ksi) {
        xp += xpp[((long)ksi * BDIM + b) * 64 + n];
        x2 += x2p[ksi * BDIM + b];
    }
    #pragma unroll
    for (int kc = 0; kc < PREPSPLIT; ++kc)
        p2 += p2p[kc * 64 + n];
    float d = x2 + p2 - 2.f * xp;
    out[b * 50 + n] = d > 0.f ? d : 0.f;
}

// ---------------- launch ----------------
extern "C" void kernel_launch(void* const* d_in, const int* in_sizes, int n_in,
                              void* d_out, int out_size, void* d_ws, size_t ws_size,
                              hipStream_t stream) {
    const float* x = (const float*)d_in[0];
    const float* proto = (const float*)d_in[1];
    float* out = (float*)d_out;

    char* ws = (char*)d_ws;
    // ws layout (bytes):
    //   [0)           proto_bf16: 64*28672*2      = 3,670,016
    //   [3,670,016)   p2p:        8*64*4          = 2,048
    //   [3,672,064)   x2p:        32*2048*4       = 262,144
    //   [3,934,208)   xpp:        32*2048*64*4    = 16,777,216   (total ~20.7 MB)
    bf16_t* pb  = (bf16_t*)(ws);
    float*  p2p = (float*)(ws + 3670016);
    float*  x2p = (float*)(ws + 3672064);
    float*  xpp = (float*)(ws + 3934208);

    proto_prep<<<dim3(64, PREPSPLIT), 256, 0, stream>>>(proto, pb, p2p);
    proto_main<<<dim3(32, KSPLIT), 256, 0, stream>>>(x, pb, xpp, x2p);
    proto_finalize<<<(BDIM * 64) / 256, 256, 0, stream>>>(xpp, x2p, p2p, out);
}

// Round 5
// 337.206 us; speedup vs baseline: 1.0868x; 1.0100x over previous
//
#include <hip/hip_runtime.h>
#include <hip/hip_bf16.h>

// Problem: B=2048, P=50, C=512, H=7, W=8  ->  M=2048, N=50 (pad 64), K=28672
//   out[b,p] = relu( sum_k x[b,k]^2 + sum_k p[p,k]^2 - 2 * sum_k x[b,k]*p[p,k] )
//
// Round-5: prototype pre-swizzled into MFMA B-fragment order (pb2), so each
// B fragment load in the main loop is ONE coalesced 1KB segment instead of
// 16 scattered rows (TA line-lookups per CU-iter 1536 -> ~1024: un-saturates
// the address pipe that was starving HBM issue). A path unchanged: coalesced
// register staging, exact fp32 x^2, bf16 -> double-buffered LDS, one
// barrier/iter, depth-2 A prefetch, depth-1 B prefetch, 4 blocks/CU.

typedef __bf16 bf16_t;
typedef bf16_t bf16x8 __attribute__((ext_vector_type(8)));
typedef float  floatx4 __attribute__((ext_vector_type(4)));

#define KDIM 28672
#define BDIM 2048
#define KSPLIT 32
#define KCHUNK (KDIM / KSPLIT)   // 896
#define STEPS (KCHUNK / 64)      // 14 k-steps of 64 per chunk
#define ASTRIDE 72               // LDS row stride in bf16 (64 + 8 pad)
#define PREPSPLIT 8
#define PREPCHUNK (KDIM / PREPSPLIT)  // 3584 floats = 448 octets
// pb2 layout (bf16 units): chunk(ks,step) = (ks*STEPS+step)*4096
//   + half*2048 + ntile*512 + lane*8 + j
//   where lane = q*16 + (p&15), ntile = p>>4, k = ks*896+step*64+half*32+q*8+j

// ---------------- kernel 1: prototype -> swizzled bf16 pb2, p2 partials -----
// grid (64, 8): blockIdx.x = p, blockIdx.y = k-chunk (1/8 of K)
__global__ __launch_bounds__(256) void proto_prep(const float* __restrict__ proto,
                                                  bf16_t* __restrict__ pb2,
                                                  float* __restrict__ p2p) {
    const int p = blockIdx.x;   // 0..63
    const int kc = blockIdx.y;  // 0..7
    const int t = threadIdx.x;  // 0..255
    const int nt = p >> 4;
    const int lr = p & 15;
    float acc = 0.f;

    for (int i = t; i < PREPCHUNK / 8; i += 256) {   // one 8-float octet per iter
        const int kg = kc * PREPCHUNK + i * 8;       // global k of octet start
        bf16x8 o;
        if (p < 50) {
            const float* src = proto + (long)p * KDIM + kg;
            floatx4 v0 = *(const floatx4*)(src);
            floatx4 v1 = *(const floatx4*)(src + 4);
            acc += v0[0]*v0[0] + v0[1]*v0[1] + v0[2]*v0[2] + v0[3]*v0[3]
                 + v1[0]*v1[0] + v1[1]*v1[1] + v1[2]*v1[2] + v1[3]*v1[3];
            o[0]=(bf16_t)v0[0]; o[1]=(bf16_t)v0[1]; o[2]=(bf16_t)v0[2]; o[3]=(bf16_t)v0[3];
            o[4]=(bf16_t)v1[0]; o[5]=(bf16_t)v1[1]; o[6]=(bf16_t)v1[2]; o[7]=(bf16_t)v1[3];
        } else {
            o[0]=(bf16_t)0.f; o[1]=(bf16_t)0.f; o[2]=(bf16_t)0.f; o[3]=(bf16_t)0.f;
            o[4]=(bf16_t)0.f; o[5]=(bf16_t)0.f; o[6]=(bf16_t)0.f; o[7]=(bf16_t)0.f;
        }
        const int ks   = kg / KCHUNK;
        const int kr   = kg % KCHUNK;
        const int step = kr >> 6;
        const int ko   = kr & 63;
        const int h    = ko >> 5;
        const int q    = (ko & 31) >> 3;
        const long addr = (long)(ks * STEPS + step) * 4096 + h * 2048
                        + nt * 512 + (q * 16 + lr) * 8;
        *(bf16x8*)(pb2 + addr) = o;
    }

    __shared__ float sred[256];
    sred[t] = acc;
    __syncthreads();
    for (int s = 128; s > 0; s >>= 1) {
        if (t < s) sred[t] += sred[t + s];
        __syncthreads();
    }
    if (t == 0) p2p[kc * 64 + p] = (p < 50) ? sred[0] : 0.f;
}

// ---------------- kernel 2: main fused GEMM + x2 ----------------
// grid (32, 32): blockIdx.x = M-tile (64 rows), blockIdx.y = K-split
__global__ __launch_bounds__(256, 4) void proto_main(const float* __restrict__ x,
                                                     const bf16_t* __restrict__ pb2,
                                                     float* __restrict__ xpp,
                                                     float* __restrict__ x2p) {
    __shared__ bf16_t As[2][64 * ASTRIDE];   // 2 x 9216 B

    const int t = threadIdx.x;
    const int lane = t & 63;
    const int wave = t >> 6;
    const int lr = lane & 15;
    const int q  = lane >> 4;
    const int mbase = blockIdx.x * 64;
    const int ks = blockIdx.y;
    const int kbase = ks * KCHUNK;

    // ---- staging role: 4 threads per row, 16 consecutive floats each ----
    const int srow = t >> 2;
    const int sq   = t & 3;
    const float* xrow = x + (long)(mbase + srow) * KDIM + kbase + sq * 16;
    bf16_t* const awr[2] = { &As[0][srow * ASTRIDE + sq * 16],
                             &As[1][srow * ASTRIDE + sq * 16] };

    // ---- compute role: 2x2 wave split over 64x64 tile ----
    const int m0 = (wave >> 1) * 32;
    const int n0 = (wave & 1) * 32;
    const int t0 = (wave & 1) * 2;               // first ntile of this wave
    // coalesced fragment stream: chunk base for this (ks), lane offset baked in
    const bf16_t* bbase = pb2 + (long)ks * STEPS * 4096 + lane * 8;
    const int ard0 = (m0 + lr) * ASTRIDE + q * 8;
    const int ard1 = (m0 + 16 + lr) * ASTRIDE + q * 8;

    floatx4 acc00 = {0.f,0.f,0.f,0.f};
    floatx4 acc01 = {0.f,0.f,0.f,0.f};
    floatx4 acc10 = {0.f,0.f,0.f,0.f};
    floatx4 acc11 = {0.f,0.f,0.f,0.f};
    float x2acc = 0.f;

    // ---- prologue ----
    floatx4 c0 = *(const floatx4*)(xrow);
    floatx4 c1 = *(const floatx4*)(xrow + 4);
    floatx4 c2 = *(const floatx4*)(xrow + 8);
    floatx4 c3 = *(const floatx4*)(xrow + 12);
    // step 0 B fragments (coalesced 1KB segments)
    bf16x8 bc00 = *(const bf16x8*)(bbase + t0 * 512);             // (t0, half0)
    bf16x8 bc01 = *(const bf16x8*)(bbase + 2048 + t0 * 512);      // (t0, half1)
    bf16x8 bc10 = *(const bf16x8*)(bbase + (t0 + 1) * 512);       // (t1, half0)
    bf16x8 bc11 = *(const bf16x8*)(bbase + 2048 + (t0 + 1) * 512);// (t1, half1)
    {
        x2acc += c0[0]*c0[0] + c0[1]*c0[1] + c0[2]*c0[2] + c0[3]*c0[3]
               + c1[0]*c1[0] + c1[1]*c1[1] + c1[2]*c1[2] + c1[3]*c1[3]
               + c2[0]*c2[0] + c2[1]*c2[1] + c2[2]*c2[2] + c2[3]*c2[3]
               + c3[0]*c3[0] + c3[1]*c3[1] + c3[2]*c3[2] + c3[3]*c3[3];
        bf16x8 lo, hi;
        lo[0]=(bf16_t)c0[0]; lo[1]=(bf16_t)c0[1]; lo[2]=(bf16_t)c0[2]; lo[3]=(bf16_t)c0[3];
        lo[4]=(bf16_t)c1[0]; lo[5]=(bf16_t)c1[1]; lo[6]=(bf16_t)c1[2]; lo[7]=(bf16_t)c1[3];
        hi[0]=(bf16_t)c2[0]; hi[1]=(bf16_t)c2[1]; hi[2]=(bf16_t)c2[2]; hi[3]=(bf16_t)c2[3];
        hi[4]=(bf16_t)c3[0]; hi[5]=(bf16_t)c3[1]; hi[6]=(bf16_t)c3[2]; hi[7]=(bf16_t)c3[3];
        *(bf16x8*)(awr[0])     = lo;
        *(bf16x8*)(awr[0] + 8) = hi;
    }
    // step 1 A -> regs
    c0 = *(const floatx4*)(xrow + 64);
    c1 = *(const floatx4*)(xrow + 68);
    c2 = *(const floatx4*)(xrow + 72);
    c3 = *(const floatx4*)(xrow + 76);
    __syncthreads();

    // ---- main loop: MFMA step it (LDS[it&1] + B regs), convert step it+1,
    //      prefetch A step it+2 / B step it+1. ONE barrier per iter. ----
    #pragma unroll 2
    for (int it = 0; it < STEPS; ++it) {
        const int buf = it & 1;

        // B prefetch: step it+1 (coalesced, L2/L1-resident)
        const int n1 = (it + 1 < STEPS ? it + 1 : STEPS - 1);
        const bf16_t* bp = bbase + n1 * 4096;
        bf16x8 bn00 = *(const bf16x8*)(bp + t0 * 512);
        bf16x8 bn01 = *(const bf16x8*)(bp + 2048 + t0 * 512);
        bf16x8 bn10 = *(const bf16x8*)(bp + (t0 + 1) * 512);
        bf16x8 bn11 = *(const bf16x8*)(bp + 2048 + (t0 + 1) * 512);

        // A prefetch: step it+2 (HBM; 2 iters of slack)
        const int nk2 = (it + 2 < STEPS ? it + 2 : STEPS - 1) * 64;
        floatx4 n0v = *(const floatx4*)(xrow + nk2);
        floatx4 n1v = *(const floatx4*)(xrow + nk2 + 4);
        floatx4 n2v = *(const floatx4*)(xrow + nk2 + 8);
        floatx4 n3v = *(const floatx4*)(xrow + nk2 + 12);

        // convert step it+1 (loaded one full iteration ago) -> LDS[buf^1]
        if (it + 1 < STEPS) {
            x2acc += c0[0]*c0[0] + c0[1]*c0[1] + c0[2]*c0[2] + c0[3]*c0[3]
                   + c1[0]*c1[0] + c1[1]*c1[1] + c1[2]*c1[2] + c1[3]*c1[3]
                   + c2[0]*c2[0] + c2[1]*c2[1] + c2[2]*c2[2] + c2[3]*c2[3]
                   + c3[0]*c3[0] + c3[1]*c3[1] + c3[2]*c3[2] + c3[3]*c3[3];
            bf16x8 lo, hi;
            lo[0]=(bf16_t)c0[0]; lo[1]=(bf16_t)c0[1]; lo[2]=(bf16_t)c0[2]; lo[3]=(bf16_t)c0[3];
            lo[4]=(bf16_t)c1[0]; lo[5]=(bf16_t)c1[1]; lo[6]=(bf16_t)c1[2]; lo[7]=(bf16_t)c1[3];
            hi[0]=(bf16_t)c2[0]; hi[1]=(bf16_t)c2[1]; hi[2]=(bf16_t)c2[2]; hi[3]=(bf16_t)c2[3];
            hi[4]=(bf16_t)c3[0]; hi[5]=(bf16_t)c3[1]; hi[6]=(bf16_t)c3[2]; hi[7]=(bf16_t)c3[3];
            *(bf16x8*)(awr[buf ^ 1])     = lo;
            *(bf16x8*)(awr[buf ^ 1] + 8) = hi;
        }

        // MFMA current step: A from LDS[buf], B from regs (loaded last iter)
        {
            const bf16_t* ab = &As[buf][0];
            bf16x8 a00 = *(const bf16x8*)(ab + ard0);
            bf16x8 a01 = *(const bf16x8*)(ab + ard0 + 32);
            bf16x8 a10 = *(const bf16x8*)(ab + ard1);
            bf16x8 a11 = *(const bf16x8*)(ab + ard1 + 32);
            acc00 = __builtin_amdgcn_mfma_f32_16x16x32_bf16(a00, bc00, acc00, 0, 0, 0);
            acc10 = __builtin_amdgcn_mfma_f32_16x16x32_bf16(a10, bc00, acc10, 0, 0, 0);
            acc01 = __builtin_amdgcn_mfma_f32_16x16x32_bf16(a00, bc10, acc01, 0, 0, 0);
            acc11 = __builtin_amdgcn_mfma_f32_16x16x32_bf16(a10, bc10, acc11, 0, 0, 0);
            acc00 = __builtin_amdgcn_mfma_f32_16x16x32_bf16(a01, bc01, acc00, 0, 0, 0);
            acc10 = __builtin_amdgcn_mfma_f32_16x16x32_bf16(a11, bc01, acc10, 0, 0, 0);
            acc01 = __builtin_amdgcn_mfma_f32_16x16x32_bf16(a01, bc11, acc01, 0, 0, 0);
            acc11 = __builtin_amdgcn_mfma_f32_16x16x32_bf16(a11, bc11, acc11, 0, 0, 0);
        }

        __syncthreads();   // LDS[buf^1] visible; LDS[buf] free next iter
        c0 = n0v; c1 = n1v; c2 = n2v; c3 = n3v;
        bc00 = bn00; bc01 = bn01; bc10 = bn10; bc11 = bn11;
    }

    // ---- xp partials: C/D layout col(n)=lane&15, row(m)=q*4+r ----
    const long base = ((long)ks * BDIM + mbase) * 64;
    #pragma unroll
    for (int r = 0; r < 4; ++r) {
        const int mr = m0 + q * 4 + r;
        xpp[base + (long)mr * 64 + n0 + lr]             = acc00[r];
        xpp[base + (long)mr * 64 + n0 + 16 + lr]        = acc01[r];
        xpp[base + (long)(mr + 16) * 64 + n0 + lr]      = acc10[r];
        xpp[base + (long)(mr + 16) * 64 + n0 + 16 + lr] = acc11[r];
    }

    // ---- x2 partials: 4 staging threads per row -> LDS reduce ----
    float* red = (float*)&As[0][0];
    red[t] = x2acc;          // safe: final loop barrier already executed
    __syncthreads();
    if (t < 64) {
        float s = red[4 * t] + red[4 * t + 1] + red[4 * t + 2] + red[4 * t + 3];
        x2p[ks * BDIM + mbase + t] = s;
    }
}

// ---------------- kernel 3: reduce split-K + epilogue ----------------
__global__ __launch_bounds__(256) void proto_finalize(const float* __restrict__ xpp,
                                                      const float* __restrict__ x2p,
                                                      const float* __restrict__ p2p,
                                                      float* __restrict__ out) {
    int idx = blockIdx.x * 256 + threadIdx.x;  // 0 .. 2048*64-1
    int b = idx >> 6;
    int n = idx & 63;
    if (n >= 50) return;
    float xp = 0.f, x2 = 0.f, p2 = 0.f;
    #pragma unroll
    for (int ksi = 0; ksi < KSPLIT; ++ksi) {
        xp += xpp[((long)ksi * BDIM + b) * 64 + n];
        x2 += x2p[ksi * BDIM + b];
    }
    #pragma unroll
    for (int kc = 0; kc < PREPSPLIT; ++kc)
        p2 += p2p[kc * 64 + n];
    float d = x2 + p2 - 2.f * xp;
    out[b * 50 + n] = d > 0.f ? d : 0.f;
}

// ---------------- launch ----------------
extern "C" void kernel_launch(void* const* d_in, const int* in_sizes, int n_in,
                              void* d_out, int out_size, void* d_ws, size_t ws_size,
                              hipStream_t stream) {
    const float* x = (const float*)d_in[0];
    const float* proto = (const float*)d_in[1];
    float* out = (float*)d_out;

    char* ws = (char*)d_ws;
    // ws layout (bytes):
    //   [0)           pb2 (swizzled): 64*28672*2  = 3,670,016
    //   [3,670,016)   p2p:        8*64*4          = 2,048
    //   [3,672,064)   x2p:        32*2048*4       = 262,144
    //   [3,934,208)   xpp:        32*2048*64*4    = 16,777,216   (total ~20.7 MB)
    bf16_t* pb2 = (bf16_t*)(ws);
    float*  p2p = (float*)(ws + 3670016);
    float*  x2p = (float*)(ws + 3672064);
    float*  xpp = (float*)(ws + 3934208);

    proto_prep<<<dim3(64, PREPSPLIT), 256, 0, stream>>>(proto, pb2, p2p);
    proto_main<<<dim3(32, KSPLIT), 256, 0, stream>>>(x, pb2, xpp, x2p);
    proto_finalize<<<(BDIM * 64) / 256, 256, 0, stream>>>(xpp, x2p, p2p, out);
}